// Round 1
// baseline (287.026 us; speedup 1.0000x reference)
//
#include <hip/hip_runtime.h>

// Problem constants
#define IN_CAPS  1152
#define IN_DIM   8
#define NUM_CAPS 10
#define DIM_CAPS 16
#define B_TOT    256

// routing-pass tiling: 768 blocks = 8 XCD chunks x 12 tiles x 8 b-blocks
#define I_T     12                 // i's per block -> 96 i-tiles
#define P_TILES (IN_CAPS / I_T)    // 96
#define B_BLK   32                 // batches per block; 2 per thread

// ws layout (floats):
//   Vbuf  [256][10][16]     = 40960
//   spart [96][256][10][16] = 3932160
//   Wt    [1152][16][2][16][4] = 2359296
//   total ~25 MB (ubuf eliminated: u_hat recomputed per pass from L2-resident x+Wt)
#define VBUF_F  (B_TOT * NUM_CAPS * DIM_CAPS)
#define SPART_F (P_TILES * B_TOT * NUM_CAPS * DIM_CAPS)

// Transpose W[n][i][d][k8] -> Wt[i][d][h][n16][c4]: per-(i,d,h) the 16 n-lanes
// read 16 contiguous float4s (2 fully-consumed lines/wave-instr).
__global__ __launch_bounds__(512) void transpose_kernel(
    const float* __restrict__ W, float* __restrict__ Wt) {
  const int i = blockIdx.x;
  const int t = threadIdx.x;
  const int n = t & 15;
  const int h = (t >> 4) & 1;
  const int d = t >> 5;
  const float4* Wf4 = (const float4*)W;
  float4* Wtf4 = (float4*)Wt;
  float4 v = make_float4(0.f, 0.f, 0.f, 0.f);
  if (n < NUM_CAPS) v = Wf4[((size_t)(n * IN_CAPS + i) * DIM_CAPS + d) * 2 + h];
  Wtf4[(size_t)i * 512 + d * 32 + h * 16 + n] = v;
}

// One routing pass that RECOMPUTES u_hat from x and Wt (both L2-resident,
// ~19 MB total) instead of streaming a 94 MB materialized ubuf from HBM.
// Load structure identical to the proven pre_kernel (2 batches/thread,
// coalesced Wt float4 reads). ZERO_V=1: V==0 -> c = 1/10 exactly (pass 0).
// XCD-aware block decode: lid%8 selects a 12-tile chunk so each XCD's L2
// holds only 1.2 MB of Wt + 1.2 MB of x.
template <int ZERO_V>
__global__ __launch_bounds__(256) void route_rc_kernel(
    const float* __restrict__ x, const float* __restrict__ Wt,
    const float* __restrict__ Vbuf, float* __restrict__ spart) {
  const int tid = threadIdx.x;
  const int n   = tid & 15;
  const int g   = tid >> 4;

  const int lid  = blockIdx.x;        // 0..767
  const int xcd  = lid & 7;
  const int r    = lid >> 3;          // 0..95
  const int tile = xcd * 12 + (r % 12);
  const int bblk = r / 12;            // 0..7
  const int b0   = bblk * B_BLK + 2 * g;
  const int i0   = tile * I_T;
  const bool active = (n < NUM_CAPS);
  const int nn = active ? n : 0;

  float V0[DIM_CAPS], V1[DIM_CAPS];
  if (!ZERO_V) {
    const float4* vp0 = (const float4*)(Vbuf + ((size_t)b0 * NUM_CAPS + nn) * DIM_CAPS);
    const float4* vp1 = (const float4*)(Vbuf + ((size_t)(b0 + 1) * NUM_CAPS + nn) * DIM_CAPS);
#pragma unroll
    for (int j = 0; j < 4; ++j) {
      float4 a = vp0[j], c = vp1[j];
      V0[4 * j + 0] = a.x; V0[4 * j + 1] = a.y; V0[4 * j + 2] = a.z; V0[4 * j + 3] = a.w;
      V1[4 * j + 0] = c.x; V1[4 * j + 1] = c.y; V1[4 * j + 2] = c.z; V1[4 * j + 3] = c.w;
    }
  }

  float s0[DIM_CAPS], s1[DIM_CAPS];
#pragma unroll
  for (int d = 0; d < DIM_CAPS; ++d) { s0[d] = 0.f; s1[d] = 0.f; }

  const float4* __restrict__ Wtp = (const float4*)Wt;
  const float4* __restrict__ xp  = (const float4*)x;

  for (int i = i0; i < i0 + I_T; ++i) {
    float4 xa0 = xp[(size_t)(b0 * IN_CAPS + i) * 2];
    float4 xb0 = xp[(size_t)(b0 * IN_CAPS + i) * 2 + 1];
    float4 xa1 = xp[(size_t)((b0 + 1) * IN_CAPS + i) * 2];
    float4 xb1 = xp[(size_t)((b0 + 1) * IN_CAPS + i) * 2 + 1];

    const float4* wbase = Wtp + (size_t)i * 512 + n;

    float u0[DIM_CAPS], u1[DIM_CAPS];
#pragma unroll
    for (int d = 0; d < DIM_CAPS; ++d) {
      float4 wa = wbase[d * 32];
      float4 wb = wbase[d * 32 + 16];
      u0[d] = wa.x * xa0.x + wa.y * xa0.y + wa.z * xa0.z + wa.w * xa0.w
            + wb.x * xb0.x + wb.y * xb0.y + wb.z * xb0.z + wb.w * xb0.w;
      u1[d] = wa.x * xa1.x + wa.y * xa1.y + wa.z * xa1.z + wa.w * xa1.w
            + wb.x * xb1.x + wb.y * xb1.y + wb.z * xb1.z + wb.w * xb1.w;
    }

    float c0, c1;
    if (ZERO_V) {
      c0 = 0.1f;
      c1 = 0.1f;
    } else {
      float bd0 = 0.f, bd1 = 0.f;
#pragma unroll
      for (int d = 0; d < DIM_CAPS; ++d) {
        bd0 += u0[d] * V0[d];
        bd1 += u1[d] * V1[d];
      }
      float e0 = active ? __expf(bd0) : 0.f;
      float e1 = active ? __expf(bd1) : 0.f;
      float es0 = e0, es1 = e1;
#pragma unroll
      for (int m = 1; m < 16; m <<= 1) {
        es0 += __shfl_xor(es0, m, 16);
        es1 += __shfl_xor(es1, m, 16);
      }
      c0 = e0 / es0;
      c1 = e1 / es1;
    }
#pragma unroll
    for (int d = 0; d < DIM_CAPS; ++d) {
      s0[d] += c0 * u0[d];
      s1[d] += c1 * u1[d];
    }
  }

  if (active) {
    float* sp0 = spart + ((size_t)(tile * B_TOT + b0) * NUM_CAPS + n) * DIM_CAPS;
    float* sp1 = spart + ((size_t)(tile * B_TOT + b0 + 1) * NUM_CAPS + n) * DIM_CAPS;
#pragma unroll
    for (int d = 0; d < DIM_CAPS; ++d) {
      sp0[d] = s0[d];
      sp1[d] = s1[d];
    }
  }
}

// Reduce NT partial tiles -> s; v = squash(s); V += v or out = v.
template <int NT>
__global__ void vupdate_kernel(const float* __restrict__ spart,
                               float* __restrict__ Vbuf,
                               float* __restrict__ out, int is_final) {
  const int b   = blockIdx.x;            // 0..255
  const int t   = threadIdx.x;           // 0..159 : n = t/16, d = t%16
  const int base = b * (NUM_CAPS * DIM_CAPS) + t;
  float s = 0.f;
#pragma unroll 16
  for (int tl = 0; tl < NT; ++tl) {
    s += spart[(size_t)tl * (B_TOT * NUM_CAPS * DIM_CAPS) + base];
  }
  float sq = s * s;
#pragma unroll
  for (int m = 1; m < 16; m <<= 1) sq += __shfl_xor(sq, m, 16);  // sum over d
  float norm = sqrtf(sq);
  float v = s * (sq / (1.f + sq)) / (norm + 1e-8f);
  if (is_final) {
    out[base] = v;
  } else {
    Vbuf[base] += v;
  }
}

extern "C" void kernel_launch(void* const* d_in, const int* in_sizes, int n_in,
                              void* d_out, int out_size, void* d_ws, size_t ws_size,
                              hipStream_t stream) {
  const float* x = (const float*)d_in[0];  // [256,1152,8]
  const float* W = (const float*)d_in[1];  // [1,10,1152,16,8]
  float* out   = (float*)d_out;            // [256,10,16]
  float* Vbuf  = (float*)d_ws;
  float* spart = Vbuf + VBUF_F;
  float* Wt    = spart + SPART_F;

  // zero V only (spart fully written before use)
  hipMemsetAsync(Vbuf, 0, (size_t)VBUF_F * sizeof(float), stream);

  transpose_kernel<<<IN_CAPS, 512, 0, stream>>>(W, Wt);

  // pass 0: V == 0 -> c = 0.1 exactly (softmax of zeros over 10 caps)
  route_rc_kernel<1><<<768, 256, 0, stream>>>(x, Wt, Vbuf, spart);
  vupdate_kernel<P_TILES><<<B_TOT, NUM_CAPS * DIM_CAPS, 0, stream>>>(spart, Vbuf, out, 0);

  // passes 1..3: recompute u_hat from L2-resident x + Wt, route against accumulated V
  for (int p = 1; p < 4; ++p) {
    route_rc_kernel<0><<<768, 256, 0, stream>>>(x, Wt, Vbuf, spart);
    vupdate_kernel<P_TILES><<<B_TOT, NUM_CAPS * DIM_CAPS, 0, stream>>>(spart, Vbuf, out, p == 3);
  }
}

// Round 3
// 237.296 us; speedup vs baseline: 1.2096x; 1.2096x over previous
//
#include <hip/hip_runtime.h>

// Problem constants
#define IN_CAPS  1152
#define IN_DIM   8
#define NUM_CAPS 10
#define DIM_CAPS 16
#define B_TOT    256

// routing-pass tiling: 768 blocks = 8 XCD chunks x 12 i-tiles x 8 b-blocks
#define I_T     12                 // i's per block -> 96 i-tiles
#define P_TILES (IN_CAPS / I_T)    // 96
#define B_BLK   32                 // batches per block: 4 waves x (4 bsub x 2)

// ws layout (floats):
//   Vbuf  [256][10][16]        = 40960
//   spart [96][256][10][16]    = 3932160
//   Wt2   [1152][10][16][8]    = 1474560   (i, n, d, k) -- d on lanes
#define VBUF_F  (B_TOT * NUM_CAPS * DIM_CAPS)
#define SPART_F (P_TILES * B_TOT * NUM_CAPS * DIM_CAPS)

// ---- 16-lane (d) sum reduction, pure VALU via DPP row ops (no LDS) ----
template <int CTRL>
__device__ __forceinline__ float dpp_add16(float v) {
  int p = __builtin_amdgcn_update_dpp(0, __float_as_int(v), CTRL, 0xF, 0xF, true);
  return v + __int_as_float(p);
}
__device__ __forceinline__ float red16(float v) {
  v = dpp_add16<0xB1>(v);   // quad_perm [1,0,3,2]  : xor 1
  v = dpp_add16<0x4E>(v);   // quad_perm [2,3,0,1]  : xor 2
  v = dpp_add16<0x141>(v);  // row_half_mirror      : pairs the two quads in each 8
  v = dpp_add16<0x140>(v);  // row_mirror           : pairs the two 8-groups in the row
  return v;                 // all 16 lanes hold the d-sum
}

// Transpose W[0][n][i][d][k8] -> Wt2[i][n][d][k8]: per (i,n) the 16 d-lanes
// read/write 512B contiguous.
__global__ __launch_bounds__(320) void transpose2_kernel(
    const float* __restrict__ W, float* __restrict__ Wt) {
  const int i = blockIdx.x;
  const int t = threadIdx.x;       // 320 = 10n * 16d * 2h
  const int d = t & 15;
  const int h = (t >> 4) & 1;
  const int n = t >> 5;            // 0..9
  const float4* Wf4 = (const float4*)W;
  float4* Wtf4 = (float4*)Wt;
  float4 v = Wf4[(((size_t)n * IN_CAPS + i) * DIM_CAPS + d) * 2 + h];
  Wtf4[(((size_t)i * NUM_CAPS + n) * DIM_CAPS + d) * 2 + h] = v;
}

// One routing pass, recomputing u_hat from L2-resident x + Wt2.
// Lane mapping: d = lane&15 (full 64-lane utilization, no masking).
// Each thread: 2 batches (ba, bb=ba+4); wave: 8 batches x 16 d.
// bd = u.V reduced over d via DPP; softmax over n=10 in-register.
// ZERO_V=1 (pass 0): V==0 -> c = 1/10 exactly; no softmax at all.
template <int ZERO_V>
__global__ __launch_bounds__(256) void route3_kernel(
    const float* __restrict__ x, const float* __restrict__ Wt,
    const float* __restrict__ Vbuf, float* __restrict__ spart) {
  const int tid  = threadIdx.x;
  const int d    = tid & 15;
  const int bsub = (tid >> 4) & 3;
  const int w    = tid >> 6;          // wave 0..3

  const int lid  = blockIdx.x;        // 0..767
  const int xcd  = lid & 7;
  const int r    = lid >> 3;          // 0..95
  const int tile = xcd * 12 + (r % 12);
  const int bblk = r / 12;            // 0..7
  const int i0   = tile * I_T;
  const int ba   = bblk * B_BLK + w * 8 + bsub;  // first batch
  const int bb   = ba + 4;                        // second batch

  float Va[NUM_CAPS], Vb[NUM_CAPS];
  if (!ZERO_V) {
#pragma unroll
    for (int n = 0; n < NUM_CAPS; ++n) {
      Va[n] = Vbuf[((size_t)ba * NUM_CAPS + n) * DIM_CAPS + d];
      Vb[n] = Vbuf[((size_t)bb * NUM_CAPS + n) * DIM_CAPS + d];
    }
  }

  float sa[NUM_CAPS], sb[NUM_CAPS];
#pragma unroll
  for (int n = 0; n < NUM_CAPS; ++n) { sa[n] = 0.f; sb[n] = 0.f; }

  const float4* __restrict__ Wtp = (const float4*)Wt;
  const float4* __restrict__ xp  = (const float4*)x;

  for (int i = i0; i < i0 + I_T; ++i) {
    float4 xa0 = xp[(size_t)(ba * IN_CAPS + i) * 2];
    float4 xa1 = xp[(size_t)(ba * IN_CAPS + i) * 2 + 1];
    float4 xb0 = xp[(size_t)(bb * IN_CAPS + i) * 2];
    float4 xb1 = xp[(size_t)(bb * IN_CAPS + i) * 2 + 1];

    // W base for this (i, d): float4 index ((i*10 + n)*16 + d)*2 + h
    const float4* wb = Wtp + ((size_t)i * NUM_CAPS * DIM_CAPS + d) * 2;

    float ua[NUM_CAPS], ub[NUM_CAPS];
#pragma unroll
    for (int n = 0; n < NUM_CAPS; ++n) {
      float4 w0 = wb[n * (DIM_CAPS * 2)];
      float4 w1 = wb[n * (DIM_CAPS * 2) + 1];
      ua[n] = w0.x * xa0.x + w0.y * xa0.y + w0.z * xa0.z + w0.w * xa0.w
            + w1.x * xa1.x + w1.y * xa1.y + w1.z * xa1.z + w1.w * xa1.w;
      ub[n] = w0.x * xb0.x + w0.y * xb0.y + w0.z * xb0.z + w0.w * xb0.w
            + w1.x * xb1.x + w1.y * xb1.y + w1.z * xb1.z + w1.w * xb1.w;
    }

    if (ZERO_V) {
#pragma unroll
      for (int n = 0; n < NUM_CAPS; ++n) { sa[n] += ua[n]; sb[n] += ub[n]; }
    } else {
      float ea[NUM_CAPS], eb[NUM_CAPS];
      float esa = 0.f, esb = 0.f;
#pragma unroll
      for (int n = 0; n < NUM_CAPS; ++n) {
        ea[n] = __expf(red16(ua[n] * Va[n]));
        eb[n] = __expf(red16(ub[n] * Vb[n]));
        esa += ea[n];
        esb += eb[n];
      }
      float ra = 1.f / esa, rb = 1.f / esb;
#pragma unroll
      for (int n = 0; n < NUM_CAPS; ++n) {
        sa[n] += (ea[n] * ra) * ua[n];
        sb[n] += (eb[n] * rb) * ub[n];
      }
    }
  }

  // spart[tile][b][n][d]; 16 d-lanes write 64B contiguous per (b,n)
  float* spa = spart + ((size_t)(tile * B_TOT + ba) * NUM_CAPS) * DIM_CAPS + d;
  float* spb = spart + ((size_t)(tile * B_TOT + bb) * NUM_CAPS) * DIM_CAPS + d;
  const float cs = ZERO_V ? 0.1f : 1.f;
#pragma unroll
  for (int n = 0; n < NUM_CAPS; ++n) {
    spa[n * DIM_CAPS] = cs * sa[n];
    spb[n * DIM_CAPS] = cs * sb[n];
  }
}

// Reduce NT partial tiles -> s; v = squash(s); V += v or out = v.
template <int NT>
__global__ void vupdate_kernel(const float* __restrict__ spart,
                               float* __restrict__ Vbuf,
                               float* __restrict__ out, int is_final) {
  const int b   = blockIdx.x;            // 0..255
  const int t   = threadIdx.x;           // 0..159 : n = t/16, d = t%16
  const int base = b * (NUM_CAPS * DIM_CAPS) + t;
  float s = 0.f;
#pragma unroll 16
  for (int tl = 0; tl < NT; ++tl) {
    s += spart[(size_t)tl * (B_TOT * NUM_CAPS * DIM_CAPS) + base];
  }
  float sq = s * s;
#pragma unroll
  for (int m = 1; m < 16; m <<= 1) sq += __shfl_xor(sq, m, 16);  // sum over d
  float norm = sqrtf(sq);
  float v = s * (sq / (1.f + sq)) / (norm + 1e-8f);
  if (is_final) {
    out[base] = v;
  } else {
    Vbuf[base] += v;
  }
}

extern "C" void kernel_launch(void* const* d_in, const int* in_sizes, int n_in,
                              void* d_out, int out_size, void* d_ws, size_t ws_size,
                              hipStream_t stream) {
  const float* x = (const float*)d_in[0];  // [256,1152,8]
  const float* W = (const float*)d_in[1];  // [1,10,1152,16,8]
  float* out   = (float*)d_out;            // [256,10,16]
  float* Vbuf  = (float*)d_ws;
  float* spart = Vbuf + VBUF_F;
  float* Wt2   = spart + SPART_F;

  (void)hipMemsetAsync(Vbuf, 0, (size_t)VBUF_F * sizeof(float), stream);

  transpose2_kernel<<<IN_CAPS, 320, 0, stream>>>(W, Wt2);

  // pass 0: V == 0 -> c = 0.1 exactly
  route3_kernel<1><<<768, 256, 0, stream>>>(x, Wt2, Vbuf, spart);
  vupdate_kernel<P_TILES><<<B_TOT, NUM_CAPS * DIM_CAPS, 0, stream>>>(spart, Vbuf, out, 0);

  // passes 1..3
  for (int p = 1; p < 4; ++p) {
    route3_kernel<0><<<768, 256, 0, stream>>>(x, Wt2, Vbuf, spart);
    vupdate_kernel<P_TILES><<<B_TOT, NUM_CAPS * DIM_CAPS, 0, stream>>>(spart, Vbuf, out, p == 3);
  }
}